// Round 11
// baseline (122.383 us; speedup 1.0000x reference)
//
#include <hip/hip_runtime.h>
#include <hip/hip_fp16.h>
#include <math.h>

#define BB 4
#define CC 64
#define HH 128
#define WW 128
#define OO 64
#define HWW (HH * WW)

typedef _Float16 f16x8 __attribute__((ext_vector_type(8)));
typedef float f32x4 __attribute__((ext_vector_type(4)));

// ws byte offsets (single-f16 weight fragments, ~111 KB)
#define WHF_OFF  0          // main W f16 frags: 18*4*64*8 halfs = 73728 B
#define WOMH_OFF 73728      // om W f16 frags: 18*2*64*8 halfs = 36864 B

__device__ inline __half2 u2h(unsigned u) {
    union { unsigned u; __half2 h; } c; c.u = u; return c.h;
}
__device__ inline unsigned h2u(__half2 h) {
    union { __half2 h; unsigned u; } c; c.h = h; return c.u;
}

// ---------------------------------------------------------------------------
// prep: weights -> single-f16 (RNE) A-fragments.
// chunk ch = half*9 + tap covers channels [half*32, half*32+32) of tap.
// A-frag: lane l holds W[o = og*16 + (l&15)][k = (l>>4)*8 + j].
__global__ void prep_kernel(const float* __restrict__ weight,     // (O,C,3,3)
                            const float* __restrict__ om_weight,  // (27,C,3,3)
                            unsigned short* __restrict__ whf,
                            unsigned short* __restrict__ womh)
{
    int d = blockIdx.x * 256 + threadIdx.x;
    if (d < 18 * 4 * 64 * 8) {
        int j  = d & 7;
        int l  = (d >> 3) & 63;
        int og = (d >> 9) & 3;
        int ch = d >> 11;
        int o  = og * 16 + (l & 15);
        int kk = (l >> 4) * 8 + j;
        int c  = (ch / 9) * 32 + kk;
        int tap = ch % 9;
        float w = weight[(o * CC + c) * 9 + tap];
        whf[d] = __half_as_ushort(__float2half_rn(w));
    }
    int d2 = d - 18 * 4 * 64 * 8;
    if (d2 >= 0 && d2 < 18 * 2 * 64 * 8) {
        int j  = d2 & 7;
        int l  = (d2 >> 3) & 63;
        int og = (d2 >> 9) & 1;
        int ch = d2 >> 10;
        int o  = og * 16 + (l & 15);
        int kk = (l >> 4) * 8 + j;
        int c  = (ch / 9) * 32 + kk;
        int tap = ch % 9;
        float w = (o < 27) ? om_weight[(o * CC + c) * 9 + tap] : 0.f;
        womh[d2] = __half_as_ushort(__float2half_rn(w));
    }
}

// ---------------------------------------------------------------------------
// Fused kernel: 32-pixel tiles, 128 threads = 2 waves, 5 blocks/CU.
// Wave wv owns N-subtile wv (16 pixels) and ALL 64 outputs. B-fragments
// built in-register from the packed-f16 window (lane = (pixel, k-octet)):
// zero barriers inside the om and main loops. Single-f16 W (no hi/lo).
__global__ void __launch_bounds__(128, 4)
fused_kernel(const float* __restrict__ x,     // (B,C,H,W)
             const unsigned short* __restrict__ whf,
             const unsigned short* __restrict__ womh,
             const float* __restrict__ bias,
             const float* __restrict__ om_bias,
             float* __restrict__ out)         // (B,O,H,W)
{
    __shared__ __align__(16) uint4 Xw[8 * 180];    // [oct][pos] 23,040 B
    __shared__ __align__(16) uint4 swth4[288];     // packed f16x2 weights 4,608 B
    __shared__ int   sidx[288];                    // 1,152 B
    __shared__ float omL[27 * 32];                 // 3,456 B  -> 32,256 B total

    int t    = threadIdx.x;
    int lane = t & 63;
    int wv   = t >> 6;              // 0..1

    int bid = blockIdx.x;           // b*512 + ho*4 + q
    int b   = bid >> 9;
    int r   = bid & 511;
    int ho  = r >> 2;
    int w0  = (r & 3) << 5;

    int pixl = lane & 15;
    int pix  = wv * 16 + pixl;      // this lane's pixel (within 32-pixel tile)
    int oct  = lane >> 4;           // this lane's k-octet (0..3)

    // ---------------- stage: all 64 ch -> LDS packed f16 octets ------------
    {
        const float* xb = x + (size_t)b * CC * HWW;
#pragma unroll 1
        for (int i = t; i < 8 * 180; i += 128) {
            int cg  = i / 180;
            int pos = i - cg * 180;
            int rr  = pos / 36;
            int cc2 = pos - rr * 36;
            int gy = ho - 2 + rr, gx = w0 - 2 + cc2;
            bool ok = (gy >= 0) & (gy < HH) & (gx >= 0) & (gx < WW);
            int gi = ok ? gy * WW + gx : 0;
            const float* xc = xb + (size_t)cg * 8 * HWW + gi;
            float v0 = xc[0],       v1 = xc[HWW],     v2 = xc[2 * HWW], v3 = xc[3 * HWW];
            float v4 = xc[4 * HWW], v5 = xc[5 * HWW], v6 = xc[6 * HWW], v7 = xc[7 * HWW];
            if (!ok) { v0=0.f; v1=0.f; v2=0.f; v3=0.f; v4=0.f; v5=0.f; v6=0.f; v7=0.f; }
            uint4 p;
            p.x = h2u(__floats2half2_rn(v0, v1));
            p.y = h2u(__floats2half2_rn(v2, v3));
            p.z = h2u(__floats2half2_rn(v4, v5));
            p.w = h2u(__floats2half2_rn(v6, v7));
            Xw[cg * 180 + pos] = p;
        }
    }
    __syncthreads();

    // ---------------- om conv: barrier-free, both og per wave --------------
    f32x4 accom[2];
    accom[0] = (f32x4){0.f, 0.f, 0.f, 0.f};
    accom[1] = (f32x4){0.f, 0.f, 0.f, 0.f};
    {
#pragma unroll 1
        for (int ch = 0; ch < 18; ch++) {
            int half = ch / 9;
            int tap  = ch - half * 9;
            int ky = tap / 3, kx = tap - ky * 3;
            int pos = (ky + 1) * 36 + pix + kx + 1;
            union { f16x8 v; uint4 u; } B;
            B.u = Xw[(half * 4 + oct) * 180 + pos];
            const f16x8 a0 = *(const f16x8*)&womh[((size_t)(ch * 2 + 0) * 64 + lane) * 8];
            const f16x8 a1 = *(const f16x8*)&womh[((size_t)(ch * 2 + 1) * 64 + lane) * 8];
            accom[0] = __builtin_amdgcn_mfma_f32_16x16x32_f16(a0, B.v, accom[0], 0, 0, 0);
            accom[1] = __builtin_amdgcn_mfma_f32_16x16x32_f16(a1, B.v, accom[1], 0, 0, 0);
        }
    }

    // om epilogue -> omL (each wave writes its own 16 pixels)
    {
#pragma unroll
        for (int og = 0; og < 2; og++) {
#pragma unroll
            for (int rg = 0; rg < 4; rg++) {
                int m = og * 16 + (lane >> 4) * 4 + rg;
                if (m < 27) {
                    float v = accom[og][rg] + om_bias[m];
                    if (m >= 18) v = 1.f / (1.f + expf(-v));
                    omL[m * 32 + pix] = v;
                }
            }
        }
    }
    __syncthreads();

    // phase B: sampling params per (tap, pixel) -> packed f16x2 weights
#pragma unroll 1
    for (int it = t; it < 288; it += 128) {
        int k  = it >> 5;
        int pp = it & 31;
        float oy = omL[k * 32 + pp];
        float ox = omL[(9 + k) * 32 + pp];
        float mm = omL[(18 + k) * 32 + pp];
        int ky = k / 3, kx = k - ky * 3;
        float py = oy + (float)(ho + ky - 1);
        float px = ox + (float)(w0 + pp + kx - 1);
        float fy = floorf(py), fx = floorf(px);
        float ly = py - fy, lx = px - fx;
        int y0 = (int)fy, x0 = (int)fx;
        bool vy0 = (y0 >= 0) & (y0 < HH);
        bool vy1 = (y0 + 1 >= 0) & (y0 + 1 < HH);
        bool vx0 = (x0 >= 0) & (x0 < WW);
        bool vx1 = (x0 + 1 >= 0) & (x0 + 1 < WW);
        float w00 = (vy0 & vx0) ? (1.f - ly) * (1.f - lx) * mm : 0.f;
        float w01 = (vy0 & vx1) ? (1.f - ly) * lx * mm : 0.f;
        float w10 = (vy1 & vx0) ? ly * (1.f - lx) * mm : 0.f;
        float w11 = (vy1 & vx1) ? ly * lx * mm : 0.f;
        uint4 wp;
        wp.x = h2u(__float2half2_rn(w00));
        wp.y = h2u(__float2half2_rn(w01));
        wp.z = h2u(__float2half2_rn(w10));
        wp.w = h2u(__float2half2_rn(w11));
        swth4[it] = wp;
        bool inw = (y0 >= ho - 2) & (y0 <= ho + 1) & (x0 >= w0 - 2) & (x0 <= w0 + 32);
        int y0c = min(max(y0, -8), 135);
        int x0c = min(max(x0, -8), 135);
        sidx[it] = ((y0c + 16) << 16) | ((x0c + 16) & 0xFFFF)
                 | (inw ? 0 : (int)0x80000000);
    }
    __syncthreads();

    // ---------------- main conv: barrier-free, in-register B ---------------
    f32x4 acc[4];
#pragma unroll
    for (int og = 0; og < 4; og++) acc[og] = (f32x4){0.f, 0.f, 0.f, 0.f};

    {
        int oct1 = 4 + oct;         // chunk1's k-octet
#pragma unroll 1
        for (int tap = 0; tap < 9; tap++) {
            int item = tap * 32 + pix;
            uint4 wp = swth4[item];
            int sv = sidx[item];
            int y0 = ((sv >> 16) & 0x7FFF) - 16;
            int x0 = (sv & 0xFFFF) - 16;
            // A-frags, all 4 og, both chunks (single f16)
            const f16x8 a00 = *(const f16x8*)&whf[((size_t)(tap * 4 + 0) * 64 + lane) * 8];
            const f16x8 a01 = *(const f16x8*)&whf[((size_t)(tap * 4 + 1) * 64 + lane) * 8];
            const f16x8 a02 = *(const f16x8*)&whf[((size_t)(tap * 4 + 2) * 64 + lane) * 8];
            const f16x8 a03 = *(const f16x8*)&whf[((size_t)(tap * 4 + 3) * 64 + lane) * 8];
            const f16x8 a10 = *(const f16x8*)&whf[((size_t)((9 + tap) * 4 + 0) * 64 + lane) * 8];
            const f16x8 a11 = *(const f16x8*)&whf[((size_t)((9 + tap) * 4 + 1) * 64 + lane) * 8];
            const f16x8 a12 = *(const f16x8*)&whf[((size_t)((9 + tap) * 4 + 2) * 64 + lane) * 8];
            const f16x8 a13 = *(const f16x8*)&whf[((size_t)((9 + tap) * 4 + 3) * 64 + lane) * 8];

            union { f16x8 v; uint4 u; } B0, B1;
            if (sv >= 0) {
                int o00 = (y0 - ho + 2) * 36 + (x0 - w0 + 2);
                __half2 w00 = u2h(wp.x), w01 = u2h(wp.y);
                __half2 w10 = u2h(wp.z), w11 = u2h(wp.w);
                const uint4* X0 = &Xw[oct * 180];
                uint4 c00 = X0[o00], c01 = X0[o00 + 1];
                uint4 c10 = X0[o00 + 36], c11 = X0[o00 + 37];
                __half2 vA = __hmul2(w00, u2h(c00.x));
                vA = __hfma2(w01, u2h(c01.x), vA);
                vA = __hfma2(w10, u2h(c10.x), vA);
                vA = __hfma2(w11, u2h(c11.x), vA);
                __half2 vB = __hmul2(w00, u2h(c00.y));
                vB = __hfma2(w01, u2h(c01.y), vB);
                vB = __hfma2(w10, u2h(c10.y), vB);
                vB = __hfma2(w11, u2h(c11.y), vB);
                __half2 vC = __hmul2(w00, u2h(c00.z));
                vC = __hfma2(w01, u2h(c01.z), vC);
                vC = __hfma2(w10, u2h(c10.z), vC);
                vC = __hfma2(w11, u2h(c11.z), vC);
                __half2 vD = __hmul2(w00, u2h(c00.w));
                vD = __hfma2(w01, u2h(c01.w), vD);
                vD = __hfma2(w10, u2h(c10.w), vD);
                vD = __hfma2(w11, u2h(c11.w), vD);
                B0.u.x = h2u(vA); B0.u.y = h2u(vB); B0.u.z = h2u(vC); B0.u.w = h2u(vD);
                const uint4* X1 = &Xw[oct1 * 180];
                uint4 d00 = X1[o00], d01 = X1[o00 + 1];
                uint4 d10 = X1[o00 + 36], d11 = X1[o00 + 37];
                __half2 uA = __hmul2(w00, u2h(d00.x));
                uA = __hfma2(w01, u2h(d01.x), uA);
                uA = __hfma2(w10, u2h(d10.x), uA);
                uA = __hfma2(w11, u2h(d11.x), uA);
                __half2 uB = __hmul2(w00, u2h(d00.y));
                uB = __hfma2(w01, u2h(d01.y), uB);
                uB = __hfma2(w10, u2h(d10.y), uB);
                uB = __hfma2(w11, u2h(d11.y), uB);
                __half2 uC = __hmul2(w00, u2h(d00.z));
                uC = __hfma2(w01, u2h(d01.z), uC);
                uC = __hfma2(w10, u2h(d10.z), uC);
                uC = __hfma2(w11, u2h(d11.z), uC);
                __half2 uD = __hmul2(w00, u2h(d00.w));
                uD = __hfma2(w01, u2h(d01.w), uD);
                uD = __hfma2(w10, u2h(d10.w), uD);
                uD = __hfma2(w11, u2h(d11.w), uD);
                B1.u.x = h2u(uA); B1.u.y = h2u(uB); B1.u.z = h2u(uC); B1.u.w = h2u(uD);
            } else {
                // rare escape: clamped global gather in f32 (two octets)
                float w00f = __low2float(u2h(wp.x)), w01f = __low2float(u2h(wp.y));
                float w10f = __low2float(u2h(wp.z)), w11f = __low2float(u2h(wp.w));
                int cy0 = min(max(y0, 0), HH - 1), cy1 = min(max(y0 + 1, 0), HH - 1);
                int cx0 = min(max(x0, 0), WW - 1), cx1 = min(max(x0 + 1, 0), WW - 1);
                int i00 = cy0 * WW + cx0, i01 = cy0 * WW + cx1;
                int i10 = cy1 * WW + cx0, i11 = cy1 * WW + cx1;
                float vv[8], uu[8];
                const float* xg0 = x + ((size_t)(b * CC + oct * 8)) * HWW;
                const float* xg1 = x + ((size_t)(b * CC + oct1 * 8)) * HWW;
#pragma unroll
                for (int j = 0; j < 8; j++) {
                    const float* xc = xg0 + (size_t)j * HWW;
                    vv[j] = w00f * xc[i00] + w01f * xc[i01]
                          + w10f * xc[i10] + w11f * xc[i11];
                    const float* xd = xg1 + (size_t)j * HWW;
                    uu[j] = w00f * xd[i00] + w01f * xd[i01]
                          + w10f * xd[i10] + w11f * xd[i11];
                }
                B0.u.x = h2u(__floats2half2_rn(vv[0], vv[1]));
                B0.u.y = h2u(__floats2half2_rn(vv[2], vv[3]));
                B0.u.z = h2u(__floats2half2_rn(vv[4], vv[5]));
                B0.u.w = h2u(__floats2half2_rn(vv[6], vv[7]));
                B1.u.x = h2u(__floats2half2_rn(uu[0], uu[1]));
                B1.u.y = h2u(__floats2half2_rn(uu[2], uu[3]));
                B1.u.z = h2u(__floats2half2_rn(uu[4], uu[5]));
                B1.u.w = h2u(__floats2half2_rn(uu[6], uu[7]));
            }
            acc[0] = __builtin_amdgcn_mfma_f32_16x16x32_f16(a00, B0.v, acc[0], 0, 0, 0);
            acc[1] = __builtin_amdgcn_mfma_f32_16x16x32_f16(a01, B0.v, acc[1], 0, 0, 0);
            acc[2] = __builtin_amdgcn_mfma_f32_16x16x32_f16(a02, B0.v, acc[2], 0, 0, 0);
            acc[3] = __builtin_amdgcn_mfma_f32_16x16x32_f16(a03, B0.v, acc[3], 0, 0, 0);
            acc[0] = __builtin_amdgcn_mfma_f32_16x16x32_f16(a10, B1.v, acc[0], 0, 0, 0);
            acc[1] = __builtin_amdgcn_mfma_f32_16x16x32_f16(a11, B1.v, acc[1], 0, 0, 0);
            acc[2] = __builtin_amdgcn_mfma_f32_16x16x32_f16(a12, B1.v, acc[2], 0, 0, 0);
            acc[3] = __builtin_amdgcn_mfma_f32_16x16x32_f16(a13, B1.v, acc[3], 0, 0, 0);
        }
    }

    // epilogue: each wave writes its 16 pixels x all 64 outputs
    int prow = ho * WW + w0;
#pragma unroll
    for (int og = 0; og < 4; og++) {
#pragma unroll
        for (int rg = 0; rg < 4; rg++) {
            int o = og * 16 + (lane >> 4) * 4 + rg;
            out[((size_t)(b * OO + o)) * HWW + prow + pix] = acc[og][rg] + bias[o];
        }
    }
}

// ---------------------------------------------------------------------------
extern "C" void kernel_launch(void* const* d_in, const int* in_sizes, int n_in,
                              void* d_out, int out_size, void* d_ws, size_t ws_size,
                              hipStream_t stream)
{
    (void)in_sizes; (void)n_in; (void)out_size; (void)ws_size;
    const float* x      = (const float*)d_in[0];
    const float* weight = (const float*)d_in[1];
    const float* bias   = (const float*)d_in[2];
    const float* om_w   = (const float*)d_in[3];
    const float* om_b   = (const float*)d_in[4];
    float* out = (float*)d_out;
    char*  ws  = (char*)d_ws;

    unsigned short* whf  = (unsigned short*)(ws + WHF_OFF);
    unsigned short* womh = (unsigned short*)(ws + WOMH_OFF);

    int prep_n = 18 * 4 * 64 * 8 + 18 * 2 * 64 * 8;  // 55296
    prep_kernel<<<(prep_n + 255) / 256, 256, 0, stream>>>(weight, om_w, whf, womh);

    int nblk = BB * HH * (WW / 32);  // 2048
    fused_kernel<<<nblk, 128, 0, stream>>>(x, whf, womh, bias, om_b, out);
}

// Round 12
// 109.832 us; speedup vs baseline: 1.1143x; 1.1143x over previous
//
#include <hip/hip_runtime.h>
#include <hip/hip_fp16.h>
#include <math.h>

#define BB 4
#define CC 64
#define HH 128
#define WW 128
#define OO 64
#define HWW (HH * WW)

typedef _Float16 f16x8 __attribute__((ext_vector_type(8)));
typedef float f32x4 __attribute__((ext_vector_type(4)));

// ws byte offsets (single-f16 weight fragments, ~111 KB)
#define WHF_OFF  0          // main W f16 frags: 18*4*64*8 halfs = 73728 B
#define WOMH_OFF 73728      // om W f16 frags: 18*2*64*8 halfs = 36864 B

__device__ inline __half2 u2h(unsigned u) {
    union { unsigned u; __half2 h; } c; c.u = u; return c.h;
}
__device__ inline unsigned h2u(__half2 h) {
    union { __half2 h; unsigned u; } c; c.h = h; return c.u;
}

// ---------------------------------------------------------------------------
// prep: weights -> single-f16 (RNE) A-fragments.
// chunk ch = half*9 + tap covers channels [half*32, half*32+32) of tap.
// A-frag: lane l holds W[o = og*16 + (l&15)][k = (l>>4)*8 + j].
__global__ void prep_kernel(const float* __restrict__ weight,     // (O,C,3,3)
                            const float* __restrict__ om_weight,  // (27,C,3,3)
                            unsigned short* __restrict__ whf,
                            unsigned short* __restrict__ womh)
{
    int d = blockIdx.x * 256 + threadIdx.x;
    if (d < 18 * 4 * 64 * 8) {
        int j  = d & 7;
        int l  = (d >> 3) & 63;
        int og = (d >> 9) & 3;
        int ch = d >> 11;
        int o  = og * 16 + (l & 15);
        int kk = (l >> 4) * 8 + j;
        int c  = (ch / 9) * 32 + kk;
        int tap = ch % 9;
        float w = weight[(o * CC + c) * 9 + tap];
        whf[d] = __half_as_ushort(__float2half_rn(w));
    }
    int d2 = d - 18 * 4 * 64 * 8;
    if (d2 >= 0 && d2 < 18 * 2 * 64 * 8) {
        int j  = d2 & 7;
        int l  = (d2 >> 3) & 63;
        int og = (d2 >> 9) & 1;
        int ch = d2 >> 10;
        int o  = og * 16 + (l & 15);
        int kk = (l >> 4) * 8 + j;
        int c  = (ch / 9) * 32 + kk;
        int tap = ch % 9;
        float w = (o < 27) ? om_weight[(o * CC + c) * 9 + tap] : 0.f;
        womh[d2] = __half_as_ushort(__float2half_rn(w));
    }
}

// ---------------------------------------------------------------------------
// Fused kernel: 32-pixel tiles, 256 threads = 4 waves, 4 blocks/CU.
// Window [oct][pos] uint4 (8 packed-f16 channels). Whole-tap exchange
// (9 barriers). Wave split: wave wv covers og-pair (wv>>1) on N-subtile
// (wv&1) -> 2 vex reads + 4 MFMAs per wave-tap. Single-f16 W (r11-validated).
__global__ void __launch_bounds__(256, 4)
fused_kernel(const float* __restrict__ x,     // (B,C,H,W)
             const unsigned short* __restrict__ whf,
             const unsigned short* __restrict__ womh,
             const float* __restrict__ bias,
             const float* __restrict__ om_bias,
             float* __restrict__ out)         // (B,O,H,W)
{
    __shared__ __align__(16) uint4 Xw[8 * 180];    // [oct][pos] 23,040 B
    __shared__ __align__(16) uint4 vex[2][32][9];  // [buf][pix][oct+pad] 9,216 B
    __shared__ __align__(16) uint4 swth4[288];     // packed f16x2 weights 4,608 B
    __shared__ int sidx[288];                      // 1,152 B  -> 38,016 B total

    int t    = threadIdx.x;
    int lane = t & 63;
    int wv   = t >> 6;

    int bid = blockIdx.x;           // b*512 + ho*4 + q
    int b   = bid >> 9;
    int r   = bid & 511;
    int ho  = r >> 2;
    int w0  = (r & 3) << 5;

    // ---------------- stage: all 64 ch -> LDS packed f16 octets ------------
    {
        const float* xb = x + (size_t)b * CC * HWW;
#pragma unroll 1
        for (int i = t; i < 8 * 180; i += 256) {
            int cg  = i / 180;
            int pos = i - cg * 180;
            int rr  = pos / 36;
            int cc2 = pos - rr * 36;
            int gy = ho - 2 + rr, gx = w0 - 2 + cc2;
            bool ok = (gy >= 0) & (gy < HH) & (gx >= 0) & (gx < WW);
            int gi = ok ? gy * WW + gx : 0;
            const float* xc = xb + (size_t)cg * 8 * HWW + gi;
            float v0 = xc[0],       v1 = xc[HWW],     v2 = xc[2 * HWW], v3 = xc[3 * HWW];
            float v4 = xc[4 * HWW], v5 = xc[5 * HWW], v6 = xc[6 * HWW], v7 = xc[7 * HWW];
            if (!ok) { v0=0.f; v1=0.f; v2=0.f; v3=0.f; v4=0.f; v5=0.f; v6=0.f; v7=0.f; }
            uint4 p;
            p.x = h2u(__floats2half2_rn(v0, v1));
            p.y = h2u(__floats2half2_rn(v2, v3));
            p.z = h2u(__floats2half2_rn(v4, v5));
            p.w = h2u(__floats2half2_rn(v6, v7));
            Xw[cg * 180 + pos] = p;
        }
    }
    __syncthreads();

    // ---------------- om conv: B = one b128 from window, 1 MFMA/chunk ------
    f32x4 accom = (f32x4){0.f, 0.f, 0.f, 0.f};
    {
        int og = wv & 1;
        int s  = wv >> 1;
        int pix_s = s * 16 + (lane & 15);
        int oct   = lane >> 4;          // k-octet 0..3 within chunk
#pragma unroll 1
        for (int ch = 0; ch < 18; ch++) {
            int half = ch / 9;
            int tap  = ch - half * 9;
            int ky = tap / 3, kx = tap - ky * 3;
            int pos = (ky + 1) * 36 + pix_s + kx + 1;
            union { f16x8 v; uint4 u; } B;
            B.u = Xw[(half * 4 + oct) * 180 + pos];
            const f16x8 a0 = *(const f16x8*)&womh[((size_t)(ch * 2 + og) * 64 + lane) * 8];
            accom = __builtin_amdgcn_mfma_f32_16x16x32_f16(a0, B.v, accom, 0, 0, 0);
        }
    }

    // om epilogue -> omL (union with vex region; unused until main loop)
    float* omL = (float*)&vex[0][0][0];   // 27*32 floats = 3,456 B < 9,216 B
    {
        int og = wv & 1, s = wv >> 1;
#pragma unroll
        for (int rg = 0; rg < 4; rg++) {
            int m = og * 16 + (lane >> 4) * 4 + rg;
            if (m < 27) {
                int pp = s * 16 + (lane & 15);
                float v = accom[rg] + om_bias[m];
                if (m >= 18) v = 1.f / (1.f + expf(-v));
                omL[m * 32 + pp] = v;
            }
        }
    }
    __syncthreads();

    // phase B: sampling params per (tap, pixel) -> packed f16x2 weights
#pragma unroll 1
    for (int it = t; it < 288; it += 256) {
        int k  = it >> 5;
        int pp = it & 31;
        float oy = omL[k * 32 + pp];
        float ox = omL[(9 + k) * 32 + pp];
        float mm = omL[(18 + k) * 32 + pp];
        int ky = k / 3, kx = k - ky * 3;
        float py = oy + (float)(ho + ky - 1);
        float px = ox + (float)(w0 + pp + kx - 1);
        float fy = floorf(py), fx = floorf(px);
        float ly = py - fy, lx = px - fx;
        int y0 = (int)fy, x0 = (int)fx;
        bool vy0 = (y0 >= 0) & (y0 < HH);
        bool vy1 = (y0 + 1 >= 0) & (y0 + 1 < HH);
        bool vx0 = (x0 >= 0) & (x0 < WW);
        bool vx1 = (x0 + 1 >= 0) & (x0 + 1 < WW);
        float w00 = (vy0 & vx0) ? (1.f - ly) * (1.f - lx) * mm : 0.f;
        float w01 = (vy0 & vx1) ? (1.f - ly) * lx * mm : 0.f;
        float w10 = (vy1 & vx0) ? ly * (1.f - lx) * mm : 0.f;
        float w11 = (vy1 & vx1) ? ly * lx * mm : 0.f;
        uint4 wp;
        wp.x = h2u(__float2half2_rn(w00));
        wp.y = h2u(__float2half2_rn(w01));
        wp.z = h2u(__float2half2_rn(w10));
        wp.w = h2u(__float2half2_rn(w11));
        swth4[it] = wp;
        bool inw = (y0 >= ho - 2) & (y0 <= ho + 1) & (x0 >= w0 - 2) & (x0 <= w0 + 32);
        int y0c = min(max(y0, -8), 135);
        int x0c = min(max(x0, -8), 135);
        sidx[it] = ((y0c + 16) << 16) | ((x0c + 16) & 0xFFFF)
                 | (inw ? 0 : (int)0x80000000);
    }
    __syncthreads();

    // ---------------- main conv: whole-tap exchange, split waves -----------
    int og2  = wv >> 1;             // og-pair: outputs [og2*32, og2*32+32)
    int s2   = wv & 1;              // N-subtile
    int pixl = lane & 15;
    int oct  = lane >> 4;

    f32x4 acc[2];                   // acc[a] = outputs (og2*2+a)*16 .. +16
    acc[0] = (f32x4){0.f, 0.f, 0.f, 0.f};
    acc[1] = (f32x4){0.f, 0.f, 0.f, 0.f};

    {
        int pix = t & 31;
        int cg  = t >> 5;               // producer octet 0..7
#pragma unroll 1
        for (int tap = 0; tap < 9; tap++) {
            int buf  = tap & 1;
            int item = tap * 32 + pix;
            uint4 wp = swth4[item];
            int sv = sidx[item];
            int y0 = ((sv >> 16) & 0x7FFF) - 16;
            int x0 = (sv & 0xFFFF) - 16;
            // A frags (single f16): og pair x both K-chunks
            const f16x8 a00 = *(const f16x8*)&whf[((size_t)(tap * 4 + og2 * 2 + 0) * 64 + lane) * 8];
            const f16x8 a01 = *(const f16x8*)&whf[((size_t)(tap * 4 + og2 * 2 + 1) * 64 + lane) * 8];
            const f16x8 a10 = *(const f16x8*)&whf[((size_t)((9 + tap) * 4 + og2 * 2 + 0) * 64 + lane) * 8];
            const f16x8 a11 = *(const f16x8*)&whf[((size_t)((9 + tap) * 4 + og2 * 2 + 1) * 64 + lane) * 8];

            uint4 payload;
            if (sv >= 0) {
                int o00 = (y0 - ho + 2) * 36 + (x0 - w0 + 2);
                const uint4* Xrow = &Xw[cg * 180];
                uint4 c00 = Xrow[o00];
                uint4 c01 = Xrow[o00 + 1];
                uint4 c10 = Xrow[o00 + 36];
                uint4 c11 = Xrow[o00 + 37];
                __half2 w00 = u2h(wp.x), w01 = u2h(wp.y);
                __half2 w10 = u2h(wp.z), w11 = u2h(wp.w);
                __half2 vA = __hmul2(w00, u2h(c00.x));
                vA = __hfma2(w01, u2h(c01.x), vA);
                vA = __hfma2(w10, u2h(c10.x), vA);
                vA = __hfma2(w11, u2h(c11.x), vA);
                __half2 vB = __hmul2(w00, u2h(c00.y));
                vB = __hfma2(w01, u2h(c01.y), vB);
                vB = __hfma2(w10, u2h(c10.y), vB);
                vB = __hfma2(w11, u2h(c11.y), vB);
                __half2 vC = __hmul2(w00, u2h(c00.z));
                vC = __hfma2(w01, u2h(c01.z), vC);
                vC = __hfma2(w10, u2h(c10.z), vC);
                vC = __hfma2(w11, u2h(c11.z), vC);
                __half2 vD = __hmul2(w00, u2h(c00.w));
                vD = __hfma2(w01, u2h(c01.w), vD);
                vD = __hfma2(w10, u2h(c10.w), vD);
                vD = __hfma2(w11, u2h(c11.w), vD);
                payload.x = h2u(vA); payload.y = h2u(vB);
                payload.z = h2u(vC); payload.w = h2u(vD);
            } else {
                // rare escape: clamped global gather in f32 (8 channels)
                const float* xg = x + ((size_t)(b * CC + cg * 8)) * HWW;
                float w00f = __low2float(u2h(wp.x)), w01f = __low2float(u2h(wp.y));
                float w10f = __low2float(u2h(wp.z)), w11f = __low2float(u2h(wp.w));
                int cy0 = min(max(y0, 0), HH - 1), cy1 = min(max(y0 + 1, 0), HH - 1);
                int cx0 = min(max(x0, 0), WW - 1), cx1 = min(max(x0 + 1, 0), WW - 1);
                int i00 = cy0 * WW + cx0, i01 = cy0 * WW + cx1;
                int i10 = cy1 * WW + cx0, i11 = cy1 * WW + cx1;
                float vv[8];
#pragma unroll
                for (int j = 0; j < 8; j++) {
                    const float* xc = xg + (size_t)j * HWW;
                    vv[j] = w00f * xc[i00] + w01f * xc[i01]
                          + w10f * xc[i10] + w11f * xc[i11];
                }
                payload.x = h2u(__floats2half2_rn(vv[0], vv[1]));
                payload.y = h2u(__floats2half2_rn(vv[2], vv[3]));
                payload.z = h2u(__floats2half2_rn(vv[4], vv[5]));
                payload.w = h2u(__floats2half2_rn(vv[6], vv[7]));
            }
            vex[buf][pix][cg] = payload;
            __syncthreads();
            {
                union { f16x8 v; uint4 u; } B0, B1;
                B0.u = vex[buf][s2 * 16 + pixl][oct];       // chunk0: octets 0..3
                B1.u = vex[buf][s2 * 16 + pixl][4 + oct];   // chunk1: octets 4..7
                acc[0] = __builtin_amdgcn_mfma_f32_16x16x32_f16(a00, B0.v, acc[0], 0, 0, 0);
                acc[1] = __builtin_amdgcn_mfma_f32_16x16x32_f16(a01, B0.v, acc[1], 0, 0, 0);
                acc[0] = __builtin_amdgcn_mfma_f32_16x16x32_f16(a10, B1.v, acc[0], 0, 0, 0);
                acc[1] = __builtin_amdgcn_mfma_f32_16x16x32_f16(a11, B1.v, acc[1], 0, 0, 0);
            }
        }
    }

    // epilogue: wave writes its og-pair on its subtile
    int prow = ho * WW + w0;
#pragma unroll
    for (int a = 0; a < 2; a++) {
#pragma unroll
        for (int rg = 0; rg < 4; rg++) {
            int o  = (og2 * 2 + a) * 16 + (lane >> 4) * 4 + rg;
            int pp = s2 * 16 + pixl;
            out[((size_t)(b * OO + o)) * HWW + prow + pp] = acc[a][rg] + bias[o];
        }
    }
}

// ---------------------------------------------------------------------------
extern "C" void kernel_launch(void* const* d_in, const int* in_sizes, int n_in,
                              void* d_out, int out_size, void* d_ws, size_t ws_size,
                              hipStream_t stream)
{
    (void)in_sizes; (void)n_in; (void)out_size; (void)ws_size;
    const float* x      = (const float*)d_in[0];
    const float* weight = (const float*)d_in[1];
    const float* bias   = (const float*)d_in[2];
    const float* om_w   = (const float*)d_in[3];
    const float* om_b   = (const float*)d_in[4];
    float* out = (float*)d_out;
    char*  ws  = (char*)d_ws;

    unsigned short* whf  = (unsigned short*)(ws + WHF_OFF);
    unsigned short* womh = (unsigned short*)(ws + WOMH_OFF);

    int prep_n = 18 * 4 * 64 * 8 + 18 * 2 * 64 * 8;  // 55296
    prep_kernel<<<(prep_n + 255) / 256, 256, 0, stream>>>(weight, om_w, whf, womh);

    int nblk = BB * HH * (WW / 32);  // 2048
    fused_kernel<<<nblk, 256, 0, stream>>>(x, whf, womh, bias, om_b, out);
}